// Round 6
// baseline (818.320 us; speedup 1.0000x reference)
//
#include <hip/hip_runtime.h>
#include <float.h>

// Viterbi decode: B=1024, T=1024, K=48.
// R6: bptr-based pipeline (serial-latency bwd eliminated).
// fwd_bp: R4-proven structure (single wave, LDS b128 same-address broadcast,
//   exec-masked to 48 lanes, 8-row double-buffered feat prefetch, tr pinned)
//   + argmax tracking via 4 interleaved strict-> compare/select chains of 12
//   (exact np.argmax first-max tie semantics). Stores bptr bytes (48MB) --
//   no mx array (cuts 192MB of writes).
// bwd: chunk-parallel backtrack (was the fallback path): bwd_map builds each
//   64-step chunk's 48->48 tag map by shuffle-chasing all 48 hypotheses at
//   once; bwd_entry composes the 16 maps; bwd_emit replays with known entry
//   tags. ~25-40us total vs ~270us serial equality-vote backtrack.
// FALLBACK (ws too small for bptr+aux): R4 mx-equality path, unchanged.

#define BB 1024
#define TT 1024
#define KK 48
#define CC 16
#define LL 64
#define NEGV -10000.0f

__device__ __forceinline__ float rdlane(float v, int l) {
  return __int_as_float(__builtin_amdgcn_readlane(__float_as_int(v), l));
}
__device__ __forceinline__ float max3f(float a, float b, float c) {
  return fmaxf(fmaxf(a, b), c);
}

// ---------------- main path: fwd with backpointers ----------------

// Step: 12x float4 same-address LDS broadcast of fv, then 4 interleaved
// strict-> argmax chains over p-subranges [0,12)[12,24)[24,36)[36,48).
// Tie semantics == np.argmax (first max): within-chain strict >, cross-chain
// combines prefer the lower-index chain on equality.
#define BSTEP(T_, FEAT_)                                                   \
  {                                                                        \
    float fvr[KK];                                                         \
    _Pragma("unroll") for (int j = 0; j < 12; ++j) {                       \
      float4 v4 = *(const float4*)(&fvbuf[4 * j]);                         \
      fvr[4 * j + 0] = v4.x; fvr[4 * j + 1] = v4.y;                        \
      fvr[4 * j + 2] = v4.z; fvr[4 * j + 3] = v4.w;                        \
    }                                                                      \
    float bs0 = fvr[0] + tr[0], bs1 = fvr[12] + tr[12];                    \
    float bs2 = fvr[24] + tr[24], bs3 = fvr[36] + tr[36];                  \
    int bi0 = 0, bi1 = 12, bi2 = 24, bi3 = 36;                             \
    _Pragma("unroll") for (int p = 1; p < 12; ++p) {                       \
      float s0 = fvr[p] + tr[p];                                           \
      float s1 = fvr[12 + p] + tr[12 + p];                                 \
      float s2 = fvr[24 + p] + tr[24 + p];                                 \
      float s3 = fvr[36 + p] + tr[36 + p];                                 \
      if (s0 > bs0) { bs0 = s0; bi0 = p; }                                 \
      if (s1 > bs1) { bs1 = s1; bi1 = 12 + p; }                            \
      if (s2 > bs2) { bs2 = s2; bi2 = 24 + p; }                            \
      if (s3 > bs3) { bs3 = s3; bi3 = 36 + p; }                            \
    }                                                                      \
    bool c1 = bs1 > bs0;                                                   \
    float m01 = c1 ? bs1 : bs0; int i01 = c1 ? bi1 : bi0;                  \
    bool c3 = bs3 > bs2;                                                   \
    float m23 = c3 ? bs3 : bs2; int i23 = c3 ? bi3 : bi2;                  \
    bool cf = m23 > m01;                                                   \
    float m = cf ? m23 : m01; int bpi = cf ? i23 : i01;                    \
    bp[(size_t)(T_)*KK] = (unsigned char)bpi;                              \
    fv = m + (FEAT_);                                                      \
    __builtin_amdgcn_wave_barrier();                                       \
    fvbuf[lane] = fv;                                                      \
    __builtin_amdgcn_wave_barrier();                                       \
  }

__global__ __launch_bounds__(64, 1) void viterbi_fwd_bp(
    const float* __restrict__ feats, const float* __restrict__ trans,
    float* __restrict__ scores, unsigned char* __restrict__ bptr,
    int* __restrict__ bestArr) {
  __shared__ __align__(16) float fvbuf[64];
  const int lane = threadIdx.x;
  const int b = blockIdx.x;
  const int rl = (lane < KK) ? lane : (KK - 1);

  float tr[KK];
#pragma unroll
  for (int j = 0; j < 12; ++j) {
    float4 t4 = *(const float4*)(trans + rl * KK + 4 * j);
    tr[4 * j + 0] = t4.x; tr[4 * j + 1] = t4.y;
    tr[4 * j + 2] = t4.z; tr[4 * j + 3] = t4.w;
  }
  // pin: block rematerialization / spilling-to-memory of the transition row
#pragma unroll
  for (int j = 0; j < KK; ++j) asm volatile("" : "+v"(tr[j]));
  const float tstop = trans[(KK - 1) * KK + rl];

  const float* fp = feats + (size_t)b * TT * KK + rl;
  unsigned char* bp = bptr + (size_t)b * TT * KK + rl;

  float fv = (lane == 46) ? 0.0f : NEGV;  // F_0
  fvbuf[lane] = fv;                       // seed broadcast buffer
  __builtin_amdgcn_wave_barrier();

  // exec-mask the recurrence to the 48 live lanes (R4: neutral for perf,
  // avoids duplicate bptr stores from clamped lanes)
  if (lane < KK) {
    float fA[8], fB[8];
#pragma unroll
    for (int k = 0; k < 8; ++k) fA[k] = fp[(size_t)k * KK];

    for (int t0 = 0; t0 < TT; t0 += 16) {
      // bulk prefetch rows t0+8..t0+15 into fB
#pragma unroll
      for (int k = 0; k < 8; ++k)
        fB[k] = fp[(size_t)((t0 + 8 + k) & (TT - 1)) * KK];
#pragma unroll
      for (int u = 0; u < 8; ++u) BSTEP(t0 + u, fA[u]);
      // bulk prefetch rows t0+16..t0+23 into fA
#pragma unroll
      for (int k = 0; k < 8; ++k)
        fA[k] = fp[(size_t)((t0 + 16 + k) & (TT - 1)) * KK];
#pragma unroll
      for (int u = 0; u < 8; ++u) BSTEP(t0 + 8 + u, fB[u]);
    }
  }

  // reconverged: lanes 48..63 alive again for the shuffle reduction
  float v = (lane < KK) ? (fv + tstop) : -FLT_MAX;
  int idx = lane;
#pragma unroll
  for (int off = 32; off >= 1; off >>= 1) {
    float ov = __shfl_xor(v, off);
    int oi = __shfl_xor(idx, off);
    bool take = (ov > v) || (ov == v && oi < idx);
    v = take ? ov : v;
    idx = take ? oi : idx;
  }
  if (lane == 0) { scores[b] = v; bestArr[b] = idx; }
}

// ---------------- chunk-parallel backtrack ----------------

__global__ __launch_bounds__(256) void bwd_map(
    const unsigned char* __restrict__ bptr, unsigned char* __restrict__ cmap) {
  const int lane = threadIdx.x & 63;
  const int wg = blockIdx.x * 4 + (threadIdx.x >> 6);
  const int b = wg >> 4;
  const int c = wg & (CC - 1);
  const int rl = (lane < KK) ? lane : (KK - 1);
  const unsigned char* bp = bptr + ((size_t)b * TT + (size_t)c * LL) * KK + rl;

  int x = rl;
  const int CH = 16;
  int cur[CH], nxt[CH];
#pragma unroll
  for (int j = 0; j < CH; ++j) cur[j] = bp[(size_t)(LL - CH + j) * KK];
  for (int tb = LL - CH; tb >= 0; tb -= CH) {
    if (tb >= CH) {
#pragma unroll
      for (int j = 0; j < CH; ++j) nxt[j] = bp[(size_t)(tb - CH + j) * KK];
    }
#pragma unroll
    for (int j = CH - 1; j >= 0; --j) x = __shfl(cur[j], x);
    if (tb >= CH) {
#pragma unroll
      for (int j = 0; j < CH; ++j) cur[j] = nxt[j];
    }
  }
  if (lane < KK) cmap[(size_t)wg * KK + lane] = (unsigned char)x;
}

__global__ __launch_bounds__(256) void bwd_entry(
    const unsigned char* __restrict__ cmap, const int* __restrict__ bestArr,
    int* __restrict__ entry) {
  const int lane = threadIdx.x & 63;
  const int b = blockIdx.x * 4 + (threadIdx.x >> 6);
  const int rl = (lane < KK) ? lane : (KK - 1);

  int rows[CC];
#pragma unroll
  for (int c = 0; c < CC; ++c) rows[c] = cmap[((size_t)b * CC + c) * KK + rl];

  int tag = bestArr[b];
  int ev = 0;
#pragma unroll
  for (int c = CC - 1; c >= 0; --c) {
    if (lane == c) ev = tag;
    tag = __shfl(rows[c], tag);
  }
  if (lane < CC) entry[b * CC + lane] = ev;
}

__global__ __launch_bounds__(256) void bwd_emit(
    const unsigned char* __restrict__ bptr, const int* __restrict__ entry,
    float* __restrict__ path) {
  const int lane = threadIdx.x & 63;
  const int wg = blockIdx.x * 4 + (threadIdx.x >> 6);
  const int b = wg >> 4;
  const int c = wg & (CC - 1);
  const int rl = (lane < KK) ? lane : (KK - 1);
  const unsigned char* bp = bptr + ((size_t)b * TT + (size_t)c * LL) * KK + rl;

  int x = entry[b * CC + c];
  int myv = 0;
  const int CH = 16;
  int cur[CH], nxt[CH];
#pragma unroll
  for (int j = 0; j < CH; ++j) cur[j] = bp[(size_t)(LL - CH + j) * KK];
  for (int tb = LL - CH; tb >= 0; tb -= CH) {
    if (tb >= CH) {
#pragma unroll
      for (int j = 0; j < CH; ++j) nxt[j] = bp[(size_t)(tb - CH + j) * KK];
    }
#pragma unroll
    for (int j = CH - 1; j >= 0; --j) {
      if (lane == tb + j) myv = x;
      x = __shfl(cur[j], x);
    }
    if (tb >= CH) {
#pragma unroll
      for (int j = 0; j < CH; ++j) cur[j] = nxt[j];
    }
  }
  path[(size_t)b * TT + (size_t)c * LL + lane] = (float)myv;
}

// ---------------- fallback path (R4 mx-equality) ----------------

#define FSTEP(T_, FEAT_)                                                   \
  {                                                                        \
    float fvr[KK];                                                         \
    _Pragma("unroll") for (int j = 0; j < 12; ++j) {                       \
      float4 v4 = *(const float4*)(&fvbuf[4 * j]);                         \
      fvr[4 * j + 0] = v4.x; fvr[4 * j + 1] = v4.y;                        \
      fvr[4 * j + 2] = v4.z; fvr[4 * j + 3] = v4.w;                        \
    }                                                                      \
    float s_[KK];                                                          \
    _Pragma("unroll") for (int p = 0; p < KK; ++p) {                       \
      s_[p] = fvr[p] + tr[p];                                              \
    }                                                                      \
    float part[16];                                                        \
    _Pragma("unroll") for (int g = 0; g < 16; ++g) {                       \
      part[g] = max3f(s_[3 * g], s_[3 * g + 1], s_[3 * g + 2]);            \
    }                                                                      \
    float q0 = max3f(part[0], part[1], part[2]);                           \
    float q1 = max3f(part[3], part[4], part[5]);                           \
    float q2 = max3f(part[6], part[7], part[8]);                           \
    float q3 = max3f(part[9], part[10], part[11]);                         \
    float q4 = max3f(part[12], part[13], part[14]);                        \
    float m_ = fmaxf(max3f(q0, q1, q2), max3f(q3, q4, part[15]));          \
    mp[(size_t)(T_)*KK] = m_;                                              \
    fv = m_ + (FEAT_);                                                     \
    __builtin_amdgcn_wave_barrier();                                       \
    fvbuf[lane] = fv;                                                      \
    __builtin_amdgcn_wave_barrier();                                       \
  }

__global__ __launch_bounds__(64, 1) void viterbi_fwd_mx(
    const float* __restrict__ feats, const float* __restrict__ trans,
    float* __restrict__ scores, float* __restrict__ mx,
    int* __restrict__ bestArr) {
  __shared__ __align__(16) float fvbuf[64];
  const int lane = threadIdx.x;
  const int b = blockIdx.x;
  const int rl = (lane < KK) ? lane : (KK - 1);

  float tr[KK];
#pragma unroll
  for (int j = 0; j < 12; ++j) {
    float4 t4 = *(const float4*)(trans + rl * KK + 4 * j);
    tr[4 * j + 0] = t4.x; tr[4 * j + 1] = t4.y;
    tr[4 * j + 2] = t4.z; tr[4 * j + 3] = t4.w;
  }
#pragma unroll
  for (int j = 0; j < KK; ++j) asm volatile("" : "+v"(tr[j]));
  const float tstop = trans[(KK - 1) * KK + rl];

  const float* fp = feats + (size_t)b * TT * KK + rl;
  float* mp = mx + (size_t)b * TT * KK + rl;

  float fv = (lane == 46) ? 0.0f : NEGV;  // F_0
  fvbuf[lane] = fv;
  __builtin_amdgcn_wave_barrier();

  if (lane < KK) {
    float fA[8], fB[8];
#pragma unroll
    for (int k = 0; k < 8; ++k) fA[k] = fp[(size_t)k * KK];

    for (int t0 = 0; t0 < TT; t0 += 16) {
#pragma unroll
      for (int k = 0; k < 8; ++k)
        fB[k] = fp[(size_t)((t0 + 8 + k) & (TT - 1)) * KK];
#pragma unroll
      for (int u = 0; u < 8; ++u) FSTEP(t0 + u, fA[u]);
#pragma unroll
      for (int k = 0; k < 8; ++k)
        fA[k] = fp[(size_t)((t0 + 16 + k) & (TT - 1)) * KK];
#pragma unroll
      for (int u = 0; u < 8; ++u) FSTEP(t0 + 8 + u, fB[u]);
    }
  }

  float v = (lane < KK) ? (fv + tstop) : -FLT_MAX;
  int idx = lane;
#pragma unroll
  for (int off = 32; off >= 1; off >>= 1) {
    float ov = __shfl_xor(v, off);
    int oi = __shfl_xor(idx, off);
    bool take = (ov > v) || (ov == v && oi < idx);
    v = take ? ov : v;
    idx = take ? oi : idx;
  }
  if (lane == 0) { scores[b] = v; bestArr[b] = idx; }
}

__global__ __launch_bounds__(64, 1) void viterbi_bwd_mx(
    const float* __restrict__ feats, const float* __restrict__ trans,
    const float* __restrict__ mx, const int* __restrict__ bestArr,
    float* __restrict__ path) {
  __shared__ float tl[KK * KK];
  const int lane = threadIdx.x;
  const int b = blockIdx.x;
  const int rl = (lane < KK) ? lane : (KK - 1);
  for (int i = lane; i < KK * KK; i += 64) tl[i] = trans[i];
  __syncthreads();

  const float* fp = feats + (size_t)b * TT * KK + rl;
  const float* mp = mx + (size_t)b * TT * KK + rl;
  int tag = bestArr[b];  // wave-uniform

  float topA = mp[(size_t)(TT - 1) * KK];  // mx_{T-1}
  float MA[8], FE[8], MB[8], FB2[8];
#pragma unroll
  for (int u = 0; u < 8; ++u) {
    MA[u] = mp[(size_t)(TT - 2 - u) * KK];
    FE[u] = fp[(size_t)(TT - 2 - u) * KK];
  }

  int myv = 0;  // lane (j&63) holds path[j]
  for (int jb = TT - 1; jb >= 15; jb -= 16) {
#pragma unroll
    for (int u = 0; u < 8; ++u) {
      int r = jb - 9 - u; int rc = r < 0 ? 0 : r;
      MB[u] = mp[(size_t)rc * KK];
      FB2[u] = fp[(size_t)rc * KK];
    }
#pragma unroll
    for (int u = 0; u < 8; ++u) {
      const int j = jb - u;
      if (lane == (j & 63)) myv = tag;
      if ((j & 63) == 0) path[(size_t)b * TT + j + lane] = (float)myv;
      float Tg = (u == 0) ? topA : MA[u - 1];
      float target = rdlane(Tg, tag);
      float s = (MA[u] + FE[u]) + tl[tag * KK + rl];
      unsigned long long bal = __ballot(s == target);
      tag = (int)__builtin_ctzll(bal);
    }
    float topB = MA[7];
#pragma unroll
    for (int u = 0; u < 8; ++u) {
      int r = jb - 17 - u; int rc = r < 0 ? 0 : r;
      MA[u] = mp[(size_t)rc * KK];
      FE[u] = fp[(size_t)rc * KK];
    }
#pragma unroll
    for (int u = 0; u < 8; ++u) {
      const int j = jb - 8 - u;
      if (lane == (j & 63)) myv = tag;
      if ((j & 63) == 0) path[(size_t)b * TT + j + lane] = (float)myv;
      float Tg = (u == 0) ? topB : MB[u - 1];
      float target = rdlane(Tg, tag);
      float s = (MB[u] + FB2[u]) + tl[tag * KK + rl];
      unsigned long long bal = __ballot(s == target);
      tag = (int)__builtin_ctzll(bal);
    }
    topA = MB[7];
  }
}

extern "C" void kernel_launch(void* const* d_in, const int* in_sizes, int n_in,
                              void* d_out, int out_size, void* d_ws,
                              size_t ws_size, hipStream_t stream) {
  const float* feats = (const float*)d_in[0];
  const float* trans = (const float*)d_in[1];
  float* out = (float*)d_out;  // [0,1024): scores; then paths [B*T]

  const size_t BP_BYTES = (size_t)BB * TT * KK;            // 48 MB
  const size_t BEST_BYTES = (size_t)BB * sizeof(int);      // 4 KB
  const size_t CMAP_BYTES = (size_t)BB * CC * KK;          // 768 KB
  const size_t ENTRY_BYTES = (size_t)BB * CC * sizeof(int);  // 64 KB
  const size_t NEED = BP_BYTES + BEST_BYTES + CMAP_BYTES + ENTRY_BYTES;

  if (ws_size >= NEED) {
    unsigned char* bptr = (unsigned char*)d_ws;
    char* p = (char*)d_ws + BP_BYTES;
    int* bestArr = (int*)p;
    p += BEST_BYTES;
    unsigned char* cmap = (unsigned char*)p;
    p += CMAP_BYTES;
    int* entry = (int*)p;

    viterbi_fwd_bp<<<dim3(BB), dim3(64), 0, stream>>>(feats, trans, out, bptr,
                                                      bestArr);
    bwd_map<<<dim3(BB * CC / 4), dim3(256), 0, stream>>>(bptr, cmap);
    bwd_entry<<<dim3(BB / 4), dim3(256), 0, stream>>>(cmap, bestArr, entry);
    bwd_emit<<<dim3(BB * CC / 4), dim3(256), 0, stream>>>(bptr, entry,
                                                          out + BB);
  } else {
    // legacy mx-equality path (needs 201MB ws)
    const size_t MX_BYTES = (size_t)BB * TT * KK * sizeof(float);
    float* mx = (float*)d_ws;
    int* bestArr = (int*)((char*)d_ws + MX_BYTES);
    viterbi_fwd_mx<<<dim3(BB), dim3(64), 0, stream>>>(feats, trans, out, mx,
                                                      bestArr);
    viterbi_bwd_mx<<<dim3(BB), dim3(64), 0, stream>>>(feats, trans, mx,
                                                      bestArr, out + BB);
  }
}

// Round 7
// 608.279 us; speedup vs baseline: 1.3453x; 1.3453x over previous
//
#include <hip/hip_runtime.h>
#include <float.h>

// Viterbi decode: B=1024, T=1024, K=48.
// fwd_mx (R4, proven 218us): single wave/block, LDS b128 same-address
//   broadcast (DS-pipe floor: B*T*13 DS ops / 256 CU ~= 222us), stores
//   pre-feat max row mx_t (exact fp32).
// bwd_mx4 (R7): serial equality-vote backtrack is ~630cyc/step with only
//   ~35cyc issue => 95% stall (LDS latency chain + vmem waits). Chains of
//   different sequences are independent -> interleave FOUR sequences' chains
//   per wave (256 blocks x 1 wave). The 4 chains' issue overlaps each
//   other's stalls regardless of stall source. Bit-exact per-chain logic
//   (same vote: s = F + tr_row == mx_j[tag] -> ballot -> ctz).
// FALLBACK (ws too small for mx): bptr pipeline (fwd_f + chunk backtrack).

#define BB 1024
#define TT 1024
#define KK 48
#define CC 16
#define LL 64
#define NEGV -10000.0f

__device__ __forceinline__ float rdlane(float v, int l) {
  return __int_as_float(__builtin_amdgcn_readlane(__float_as_int(v), l));
}
__device__ __forceinline__ float max3f(float a, float b, float c) {
  return fmaxf(fmaxf(a, b), c);
}

// ---------------- main path: fwd (R4, unchanged) ----------------

#define FSTEP(T_, FEAT_)                                                   \
  {                                                                        \
    float fvr[KK];                                                         \
    _Pragma("unroll") for (int j = 0; j < 12; ++j) {                       \
      float4 v4 = *(const float4*)(&fvbuf[4 * j]);                         \
      fvr[4 * j + 0] = v4.x; fvr[4 * j + 1] = v4.y;                        \
      fvr[4 * j + 2] = v4.z; fvr[4 * j + 3] = v4.w;                        \
    }                                                                      \
    float s_[KK];                                                          \
    _Pragma("unroll") for (int p = 0; p < KK; ++p) {                       \
      s_[p] = fvr[p] + tr[p];                                              \
    }                                                                      \
    float part[16];                                                        \
    _Pragma("unroll") for (int g = 0; g < 16; ++g) {                       \
      part[g] = max3f(s_[3 * g], s_[3 * g + 1], s_[3 * g + 2]);            \
    }                                                                      \
    float q0 = max3f(part[0], part[1], part[2]);                           \
    float q1 = max3f(part[3], part[4], part[5]);                           \
    float q2 = max3f(part[6], part[7], part[8]);                           \
    float q3 = max3f(part[9], part[10], part[11]);                         \
    float q4 = max3f(part[12], part[13], part[14]);                        \
    float m_ = fmaxf(max3f(q0, q1, q2), max3f(q3, q4, part[15]));          \
    mp[(size_t)(T_)*KK] = m_;                                              \
    fv = m_ + (FEAT_);                                                     \
    __builtin_amdgcn_wave_barrier();                                       \
    fvbuf[lane] = fv;                                                      \
    __builtin_amdgcn_wave_barrier();                                       \
  }

__global__ __launch_bounds__(64, 1) void viterbi_fwd_mx(
    const float* __restrict__ feats, const float* __restrict__ trans,
    float* __restrict__ scores, float* __restrict__ mx,
    int* __restrict__ bestArr) {
  __shared__ __align__(16) float fvbuf[64];
  const int lane = threadIdx.x;
  const int b = blockIdx.x;
  const int rl = (lane < KK) ? lane : (KK - 1);

  float tr[KK];
#pragma unroll
  for (int j = 0; j < 12; ++j) {
    float4 t4 = *(const float4*)(trans + rl * KK + 4 * j);
    tr[4 * j + 0] = t4.x; tr[4 * j + 1] = t4.y;
    tr[4 * j + 2] = t4.z; tr[4 * j + 3] = t4.w;
  }
  // pin: block rematerialization / spilling-to-memory of the transition row
#pragma unroll
  for (int j = 0; j < KK; ++j) asm volatile("" : "+v"(tr[j]));
  const float tstop = trans[(KK - 1) * KK + rl];

  const float* fp = feats + (size_t)b * TT * KK + rl;
  float* mp = mx + (size_t)b * TT * KK + rl;

  float fv = (lane == 46) ? 0.0f : NEGV;  // F_0
  fvbuf[lane] = fv;                       // seed broadcast buffer
  __builtin_amdgcn_wave_barrier();

  if (lane < KK) {
    float fA[8], fB[8];
#pragma unroll
    for (int k = 0; k < 8; ++k) fA[k] = fp[(size_t)k * KK];

    for (int t0 = 0; t0 < TT; t0 += 16) {
#pragma unroll
      for (int k = 0; k < 8; ++k)
        fB[k] = fp[(size_t)((t0 + 8 + k) & (TT - 1)) * KK];
#pragma unroll
      for (int u = 0; u < 8; ++u) FSTEP(t0 + u, fA[u]);
#pragma unroll
      for (int k = 0; k < 8; ++k)
        fA[k] = fp[(size_t)((t0 + 16 + k) & (TT - 1)) * KK];
#pragma unroll
      for (int u = 0; u < 8; ++u) FSTEP(t0 + 8 + u, fB[u]);
    }
  }

  float v = (lane < KK) ? (fv + tstop) : -FLT_MAX;
  int idx = lane;
#pragma unroll
  for (int off = 32; off >= 1; off >>= 1) {
    float ov = __shfl_xor(v, off);
    int oi = __shfl_xor(idx, off);
    bool take = (ov > v) || (ov == v && oi < idx);
    v = take ? ov : v;
    idx = take ? oi : idx;
  }
  if (lane == 0) { scores[b] = v; bestArr[b] = idx; }
}

// ---------------- bwd: 4 interleaved chains per wave (R7) ----------------

__global__ __launch_bounds__(64, 1) void viterbi_bwd_mx4(
    const float* __restrict__ feats, const float* __restrict__ trans,
    const float* __restrict__ mx, const int* __restrict__ bestArr,
    float* __restrict__ path) {
  __shared__ float tl[KK * KK];
  const int lane = threadIdx.x;
  const int rl = (lane < KK) ? lane : (KK - 1);
  const int b0 = blockIdx.x * 4;
  for (int i = lane; i < KK * KK; i += 64) tl[i] = trans[i];
  __syncthreads();

  const float* fp[4];
  const float* mp[4];
  int tg[4], mv[4];
  float tA[4];
  float MA[4][8], FE[4][8], MB[4][8], FB[4][8];

#pragma unroll
  for (int i = 0; i < 4; ++i) {
    fp[i] = feats + (size_t)(b0 + i) * TT * KK + rl;
    mp[i] = mx + (size_t)(b0 + i) * TT * KK + rl;
    tg[i] = bestArr[b0 + i];  // wave-uniform
    mv[i] = 0;
    tA[i] = mp[i][(size_t)(TT - 1) * KK];  // mx_{T-1}
#pragma unroll
    for (int u = 0; u < 8; ++u) {
      MA[i][u] = mp[i][(size_t)(TT - 2 - u) * KK];
      FE[i][u] = fp[i][(size_t)(TT - 2 - u) * KK];
    }
  }

  for (int jb = TT - 1; jb >= 15; jb -= 16) {
    // bulk load block jb-8 rows for all 4 sequences (clamped)
#pragma unroll
    for (int i = 0; i < 4; ++i)
#pragma unroll
      for (int u = 0; u < 8; ++u) {
        int r = jb - 9 - u; int rc = r < 0 ? 0 : r;
        MB[i][u] = mp[i][(size_t)rc * KK];
        FB[i][u] = fp[i][(size_t)rc * KK];
      }
    // process block jb: 4 independent vote chains interleaved per step
#pragma unroll
    for (int u = 0; u < 8; ++u) {
      const int j = jb - u;
#pragma unroll
      for (int i = 0; i < 4; ++i) {
        if (lane == (j & 63)) mv[i] = tg[i];
        if ((j & 63) == 0)
          path[(size_t)(b0 + i) * TT + j + lane] = (float)mv[i];
        float Tg = (u == 0) ? tA[i] : MA[i][u - 1];
        float target = rdlane(Tg, tg[i]);            // mx_j[tag]
        float s = (MA[i][u] + FE[i][u]) + tl[tg[i] * KK + rl];
        unsigned long long bal = __ballot(s == target);  // lanes>=48 dup 47
        tg[i] = (int)__builtin_ctzll(bal);           // first p (np.argmax)
      }
    }
    float tB[4];
#pragma unroll
    for (int i = 0; i < 4; ++i) tB[i] = MA[i][7];  // mx_{jb-8}
    // bulk load block jb-16 rows (clamped)
#pragma unroll
    for (int i = 0; i < 4; ++i)
#pragma unroll
      for (int u = 0; u < 8; ++u) {
        int r = jb - 17 - u; int rc = r < 0 ? 0 : r;
        MA[i][u] = mp[i][(size_t)rc * KK];
        FE[i][u] = fp[i][(size_t)rc * KK];
      }
    // process block jb-8
#pragma unroll
    for (int u = 0; u < 8; ++u) {
      const int j = jb - 8 - u;
#pragma unroll
      for (int i = 0; i < 4; ++i) {
        if (lane == (j & 63)) mv[i] = tg[i];
        if ((j & 63) == 0)
          path[(size_t)(b0 + i) * TT + j + lane] = (float)mv[i];
        float Tg = (u == 0) ? tB[i] : MB[i][u - 1];
        float target = rdlane(Tg, tg[i]);
        float s = (MB[i][u] + FB[i][u]) + tl[tg[i] * KK + rl];
        unsigned long long bal = __ballot(s == target);
        tg[i] = (int)__builtin_ctzll(bal);  // garbage after j==0 vote: unused
      }
    }
#pragma unroll
    for (int i = 0; i < 4; ++i) tA[i] = MB[i][7];
  }
}

// ---------------- fallback path (bptr pipeline) ----------------

__global__ __launch_bounds__(64, 1) void viterbi_fwd_f(
    const float* __restrict__ feats, const float* __restrict__ trans,
    float* __restrict__ scores, unsigned char* __restrict__ bptr,
    int* __restrict__ bestArr) {
  __shared__ __align__(16) float fvbuf[64];
  const int lane = threadIdx.x;
  const int b = blockIdx.x;
  const int rl = (lane < KK) ? lane : (KK - 1);

  float tr[KK];
#pragma unroll
  for (int j = 0; j < 12; ++j) {
    float4 t4 = *(const float4*)(trans + rl * KK + 4 * j);
    tr[4 * j + 0] = t4.x; tr[4 * j + 1] = t4.y;
    tr[4 * j + 2] = t4.z; tr[4 * j + 3] = t4.w;
  }
  const float tstop = trans[(KK - 1) * KK + rl];

  if (lane < KK) fvbuf[lane] = (lane == 46) ? 0.0f : NEGV;
  __builtin_amdgcn_wave_barrier();

  const float* fp = feats + (size_t)b * TT * KK + rl;
  unsigned char* bp = bptr + (size_t)b * TT * KK + lane;

  float fbuf[4];
#pragma unroll
  for (int k = 0; k < 4; ++k) fbuf[k] = fp[(size_t)k * KK];

  float fv = NEGV;
  for (int t0 = 0; t0 < TT; t0 += 4) {
#pragma unroll
    for (int u = 0; u < 4; ++u) {
      const int t = t0 + u;
      float fvr[KK];
#pragma unroll
      for (int j = 0; j < 12; ++j) {
        float4 v4 = *(const float4*)(&fvbuf[4 * j]);
        fvr[4 * j + 0] = v4.x; fvr[4 * j + 1] = v4.y;
        fvr[4 * j + 2] = v4.z; fvr[4 * j + 3] = v4.w;
      }
      __builtin_amdgcn_wave_barrier();

      float bs0 = fvr[0] + tr[0], bs1 = fvr[12] + tr[12];
      float bs2 = fvr[24] + tr[24], bs3 = fvr[36] + tr[36];
      int bi0 = 0, bi1 = 12, bi2 = 24, bi3 = 36;
#pragma unroll
      for (int p = 1; p < 12; ++p) {
        float s0 = fvr[p] + tr[p];
        float s1 = fvr[12 + p] + tr[12 + p];
        float s2 = fvr[24 + p] + tr[24 + p];
        float s3 = fvr[36 + p] + tr[36 + p];
        if (s0 > bs0) { bs0 = s0; bi0 = p; }
        if (s1 > bs1) { bs1 = s1; bi1 = 12 + p; }
        if (s2 > bs2) { bs2 = s2; bi2 = 24 + p; }
        if (s3 > bs3) { bs3 = s3; bi3 = 36 + p; }
      }
      bool c1 = bs1 > bs0;
      float m01 = c1 ? bs1 : bs0; int i01 = c1 ? bi1 : bi0;
      bool c3 = bs3 > bs2;
      float m23 = c3 ? bs3 : bs2; int i23 = c3 ? bi3 : bi2;
      bool cf = m23 > m01;
      float m = cf ? m23 : m01; int bpi = cf ? i23 : i01;

      float nfv = m + fbuf[u];
      int tpre = t + 4; if (tpre >= TT) tpre = 0;
      fbuf[u] = fp[(size_t)tpre * KK];

      if (lane < KK) {
        bp[(size_t)t * KK] = (unsigned char)bpi;
        fvbuf[lane] = nfv;
        fv = nfv;
      }
      __builtin_amdgcn_wave_barrier();
    }
  }

  float v = (lane < KK) ? (fv + tstop) : -FLT_MAX;
  int idx = lane;
#pragma unroll
  for (int off = 32; off >= 1; off >>= 1) {
    float ov = __shfl_xor(v, off);
    int oi = __shfl_xor(idx, off);
    bool take = (ov > v) || (ov == v && oi < idx);
    v = take ? ov : v;
    idx = take ? oi : idx;
  }
  if (lane == 0) { scores[b] = v; bestArr[b] = idx; }
}

__global__ __launch_bounds__(256) void bwd_map(
    const unsigned char* __restrict__ bptr, unsigned char* __restrict__ cmap) {
  const int lane = threadIdx.x & 63;
  const int wg = blockIdx.x * 4 + (threadIdx.x >> 6);
  const int b = wg >> 4;
  const int c = wg & (CC - 1);
  const int rl = (lane < KK) ? lane : (KK - 1);
  const unsigned char* bp = bptr + ((size_t)b * TT + (size_t)c * LL) * KK + rl;

  int x = rl;
  const int CH = 16;
  int cur[CH], nxt[CH];
#pragma unroll
  for (int j = 0; j < CH; ++j) cur[j] = bp[(size_t)(LL - CH + j) * KK];
  for (int tb = LL - CH; tb >= 0; tb -= CH) {
    if (tb >= CH) {
#pragma unroll
      for (int j = 0; j < CH; ++j) nxt[j] = bp[(size_t)(tb - CH + j) * KK];
    }
#pragma unroll
    for (int j = CH - 1; j >= 0; --j) x = __shfl(cur[j], x);
    if (tb >= CH) {
#pragma unroll
      for (int j = 0; j < CH; ++j) cur[j] = nxt[j];
    }
  }
  if (lane < KK) cmap[(size_t)wg * KK + lane] = (unsigned char)x;
}

__global__ __launch_bounds__(256) void bwd_entry(
    const unsigned char* __restrict__ cmap, const int* __restrict__ bestArr,
    int* __restrict__ entry) {
  const int lane = threadIdx.x & 63;
  const int b = blockIdx.x * 4 + (threadIdx.x >> 6);
  const int rl = (lane < KK) ? lane : (KK - 1);

  int rows[CC];
#pragma unroll
  for (int c = 0; c < CC; ++c) rows[c] = cmap[((size_t)b * CC + c) * KK + rl];

  int tag = bestArr[b];
  int ev = 0;
#pragma unroll
  for (int c = CC - 1; c >= 0; --c) {
    if (lane == c) ev = tag;
    tag = __shfl(rows[c], tag);
  }
  if (lane < CC) entry[b * CC + lane] = ev;
}

__global__ __launch_bounds__(256) void bwd_emit(
    const unsigned char* __restrict__ bptr, const int* __restrict__ entry,
    float* __restrict__ path) {
  const int lane = threadIdx.x & 63;
  const int wg = blockIdx.x * 4 + (threadIdx.x >> 6);
  const int b = wg >> 4;
  const int c = wg & (CC - 1);
  const int rl = (lane < KK) ? lane : (KK - 1);
  const unsigned char* bp = bptr + ((size_t)b * TT + (size_t)c * LL) * KK + rl;

  int x = entry[b * CC + c];
  int myv = 0;
  const int CH = 16;
  int cur[CH], nxt[CH];
#pragma unroll
  for (int j = 0; j < CH; ++j) cur[j] = bp[(size_t)(LL - CH + j) * KK];
  for (int tb = LL - CH; tb >= 0; tb -= CH) {
    if (tb >= CH) {
#pragma unroll
      for (int j = 0; j < CH; ++j) nxt[j] = bp[(size_t)(tb - CH + j) * KK];
    }
#pragma unroll
    for (int j = CH - 1; j >= 0; --j) {
      if (lane == tb + j) myv = x;
      x = __shfl(cur[j], x);
    }
    if (tb >= CH) {
#pragma unroll
      for (int j = 0; j < CH; ++j) cur[j] = nxt[j];
    }
  }
  path[(size_t)b * TT + (size_t)c * LL + lane] = (float)myv;
}

extern "C" void kernel_launch(void* const* d_in, const int* in_sizes, int n_in,
                              void* d_out, int out_size, void* d_ws,
                              size_t ws_size, hipStream_t stream) {
  const float* feats = (const float*)d_in[0];
  const float* trans = (const float*)d_in[1];
  float* out = (float*)d_out;  // [0,1024): scores; then paths [B*T]

  const size_t MX_BYTES = (size_t)BB * TT * KK * sizeof(float);  // 201.3 MB
  if (ws_size >= MX_BYTES + 4096) {
    float* mx = (float*)d_ws;
    int* bestArr = (int*)((char*)d_ws + MX_BYTES);
    viterbi_fwd_mx<<<dim3(BB), dim3(64), 0, stream>>>(feats, trans, out, mx,
                                                      bestArr);
    viterbi_bwd_mx4<<<dim3(BB / 4), dim3(64), 0, stream>>>(feats, trans, mx,
                                                           bestArr, out + BB);
  } else {
    unsigned char* bptr = (unsigned char*)d_ws;
    char* p = (char*)d_ws + (size_t)BB * TT * KK;
    int* bestArr = (int*)p;
    p += BB * sizeof(int);
    unsigned char* cmap = (unsigned char*)p;
    p += (size_t)BB * CC * KK;
    int* entry = (int*)p;

    viterbi_fwd_f<<<dim3(BB), dim3(64), 0, stream>>>(feats, trans, out, bptr,
                                                     bestArr);
    bwd_map<<<dim3(BB * CC / 4), dim3(256), 0, stream>>>(bptr, cmap);
    bwd_entry<<<dim3(BB / 4), dim3(256), 0, stream>>>(cmap, bestArr, entry);
    bwd_emit<<<dim3(BB * CC / 4), dim3(256), 0, stream>>>(bptr, entry,
                                                          out + BB);
  }
}

// Round 8
// 481.876 us; speedup vs baseline: 1.6982x; 1.2623x over previous
//
#include <hip/hip_runtime.h>
#include <float.h>

// Viterbi decode: B=1024, T=1024, K=48.
// R8: FUSED fwd+bwd, one kernel, one wave per sequence (1024 blocks).
//   Phase 1 (fwd, R4-proven body): LDS b128 same-address broadcast of fv,
//     exec-masked to 48 lanes, 8-row double-buffered feat prefetch, tr
//     pinned in regs. Writes pre-feat max rows mx_t (exact fp32) to global.
//   Terminal argmax via shuffle butterfly -> tag uniform in-register (no
//     bestArr round-trip).
//   s_waitcnt vmcnt(0): own mx stores complete (L2) before own reads.
//   Phase 2 (bwd, R1-proven body): serial equality-vote backtrack with
//     8-row ping-pong bulk loads of own mx/feat rows. 4 blocks/CU give the
//     same 4-chains-per-CU latency overlap the split version had (R7 lesson:
//     in-wave interleave adds nothing over cross-wave).
//   Fusion removes the kernel boundary (suspected 50-130us gap) and makes
//   the fused dispatch's dur_us an exact fwd+bwd measurement.
// FALLBACK (ws < 201MB): bptr pipeline (fwd_f + chunk backtrack), unchanged.

#define BB 1024
#define TT 1024
#define KK 48
#define CC 16
#define LL 64
#define NEGV -10000.0f

__device__ __forceinline__ float rdlane(float v, int l) {
  return __int_as_float(__builtin_amdgcn_readlane(__float_as_int(v), l));
}
__device__ __forceinline__ float max3f(float a, float b, float c) {
  return fmaxf(fmaxf(a, b), c);
}

// ---------------- main path: fused fwd+bwd ----------------

#define FSTEP(T_, FEAT_)                                                   \
  {                                                                        \
    float fvr[KK];                                                         \
    _Pragma("unroll") for (int j = 0; j < 12; ++j) {                       \
      float4 v4 = *(const float4*)(&fvbuf[4 * j]);                         \
      fvr[4 * j + 0] = v4.x; fvr[4 * j + 1] = v4.y;                        \
      fvr[4 * j + 2] = v4.z; fvr[4 * j + 3] = v4.w;                        \
    }                                                                      \
    float s_[KK];                                                          \
    _Pragma("unroll") for (int p = 0; p < KK; ++p) {                       \
      s_[p] = fvr[p] + tr[p];                                              \
    }                                                                      \
    float part[16];                                                        \
    _Pragma("unroll") for (int g = 0; g < 16; ++g) {                       \
      part[g] = max3f(s_[3 * g], s_[3 * g + 1], s_[3 * g + 2]);            \
    }                                                                      \
    float q0 = max3f(part[0], part[1], part[2]);                           \
    float q1 = max3f(part[3], part[4], part[5]);                           \
    float q2 = max3f(part[6], part[7], part[8]);                           \
    float q3 = max3f(part[9], part[10], part[11]);                         \
    float q4 = max3f(part[12], part[13], part[14]);                        \
    float m_ = fmaxf(max3f(q0, q1, q2), max3f(q3, q4, part[15]));          \
    mp[(size_t)(T_)*KK] = m_;                                              \
    fv = m_ + (FEAT_);                                                     \
    __builtin_amdgcn_wave_barrier();                                       \
    fvbuf[lane] = fv;                                                      \
    __builtin_amdgcn_wave_barrier();                                       \
  }

__global__ __launch_bounds__(64, 1) void viterbi_fused(
    const float* __restrict__ feats, const float* __restrict__ trans,
    float* __restrict__ scores, float* __restrict__ mx,
    float* __restrict__ path) {
  __shared__ __align__(16) float fvbuf[64];
  __shared__ float tl[KK * KK];
  const int lane = threadIdx.x;
  const int b = blockIdx.x;
  const int rl = (lane < KK) ? lane : (KK - 1);

  // trans row for fwd (lane = next), plus full trans into LDS for bwd.
  float tr[KK];
#pragma unroll
  for (int j = 0; j < 12; ++j) {
    float4 t4 = *(const float4*)(trans + rl * KK + 4 * j);
    tr[4 * j + 0] = t4.x; tr[4 * j + 1] = t4.y;
    tr[4 * j + 2] = t4.z; tr[4 * j + 3] = t4.w;
  }
#pragma unroll
  for (int j = 0; j < KK; ++j) asm volatile("" : "+v"(tr[j]));
  const float tstop = trans[(KK - 1) * KK + rl];
  for (int i = lane; i < KK * KK; i += 64) tl[i] = trans[i];

  const float* fp = feats + (size_t)b * TT * KK + rl;
  float* mp = mx + (size_t)b * TT * KK + rl;

  float fv = (lane == 46) ? 0.0f : NEGV;  // F_0
  __syncthreads();                        // tl + fvbuf ordering (single wave)
  fvbuf[lane] = fv;
  __builtin_amdgcn_wave_barrier();

  // ---------------- phase 1: forward ----------------
  if (lane < KK) {
    float fA[8], fB[8];
#pragma unroll
    for (int k = 0; k < 8; ++k) fA[k] = fp[(size_t)k * KK];

    for (int t0 = 0; t0 < TT; t0 += 16) {
#pragma unroll
      for (int k = 0; k < 8; ++k)
        fB[k] = fp[(size_t)((t0 + 8 + k) & (TT - 1)) * KK];
#pragma unroll
      for (int u = 0; u < 8; ++u) FSTEP(t0 + u, fA[u]);
#pragma unroll
      for (int k = 0; k < 8; ++k)
        fA[k] = fp[(size_t)((t0 + 16 + k) & (TT - 1)) * KK];
#pragma unroll
      for (int u = 0; u < 8; ++u) FSTEP(t0 + 8 + u, fB[u]);
    }
  }

  // terminal argmax (all 64 lanes; result uniform across wave)
  float v = (lane < KK) ? (fv + tstop) : -FLT_MAX;
  int idx = lane;
#pragma unroll
  for (int off = 32; off >= 1; off >>= 1) {
    float ov = __shfl_xor(v, off);
    int oi = __shfl_xor(idx, off);
    bool take = (ov > v) || (ov == v && oi < idx);
    v = take ? ov : v;
    idx = take ? oi : idx;
  }
  if (lane == 0) scores[b] = v;
  int tag = idx;  // wave-uniform

  // own mx stores must be L2-visible before we read them back
  asm volatile("s_waitcnt vmcnt(0)" ::: "memory");

  // ---------------- phase 2: backtrack (R1-proven) ----------------
  float topA = mp[(size_t)(TT - 1) * KK];  // mx_{T-1}
  float MA[8], FE[8], MB[8], FB2[8];
#pragma unroll
  for (int u = 0; u < 8; ++u) {
    MA[u] = mp[(size_t)(TT - 2 - u) * KK];
    FE[u] = fp[(size_t)(TT - 2 - u) * KK];
  }

  int myv = 0;  // lane (j&63) holds path[j]
  for (int jb = TT - 1; jb >= 15; jb -= 16) {
    // bulk load block jb-8 (rows jb-9-u), clamped
#pragma unroll
    for (int u = 0; u < 8; ++u) {
      int r = jb - 9 - u; int rc = r < 0 ? 0 : r;
      MB[u] = mp[(size_t)rc * KK];
      FB2[u] = fp[(size_t)rc * KK];
    }
    // process block jb with topA / MA / FE
#pragma unroll
    for (int u = 0; u < 8; ++u) {
      const int j = jb - u;
      if (lane == (j & 63)) myv = tag;
      if ((j & 63) == 0) path[(size_t)b * TT + j + lane] = (float)myv;
      float Tg = (u == 0) ? topA : MA[u - 1];
      float target = rdlane(Tg, tag);            // mx_j[tag]
      float s = (MA[u] + FE[u]) + tl[tag * KK + rl];
      unsigned long long bal = __ballot(s == target);  // lanes>=48 mirror 47
      tag = (int)__builtin_ctzll(bal);           // first p (np.argmax tie)
    }
    float topB = MA[7];  // mx_{jb-8}
    // bulk load block jb-16 (rows jb-17-u), clamped
#pragma unroll
    for (int u = 0; u < 8; ++u) {
      int r = jb - 17 - u; int rc = r < 0 ? 0 : r;
      MA[u] = mp[(size_t)rc * KK];
      FE[u] = fp[(size_t)rc * KK];
    }
    // process block jb-8 with topB / MB / FB2
#pragma unroll
    for (int u = 0; u < 8; ++u) {
      const int j = jb - 8 - u;
      if (lane == (j & 63)) myv = tag;
      if ((j & 63) == 0) path[(size_t)b * TT + j + lane] = (float)myv;
      float Tg = (u == 0) ? topB : MB[u - 1];
      float target = rdlane(Tg, tag);
      float s = (MB[u] + FB2[u]) + tl[tag * KK + rl];
      unsigned long long bal = __ballot(s == target);
      tag = (int)__builtin_ctzll(bal);  // garbage after j==0 vote: unused
    }
    topA = MB[7];
  }
}

// ---------------- fallback path (bptr pipeline) ----------------

__global__ __launch_bounds__(64, 1) void viterbi_fwd_f(
    const float* __restrict__ feats, const float* __restrict__ trans,
    float* __restrict__ scores, unsigned char* __restrict__ bptr,
    int* __restrict__ bestArr) {
  __shared__ __align__(16) float fvbuf[64];
  const int lane = threadIdx.x;
  const int b = blockIdx.x;
  const int rl = (lane < KK) ? lane : (KK - 1);

  float tr[KK];
#pragma unroll
  for (int j = 0; j < 12; ++j) {
    float4 t4 = *(const float4*)(trans + rl * KK + 4 * j);
    tr[4 * j + 0] = t4.x; tr[4 * j + 1] = t4.y;
    tr[4 * j + 2] = t4.z; tr[4 * j + 3] = t4.w;
  }
  const float tstop = trans[(KK - 1) * KK + rl];

  if (lane < KK) fvbuf[lane] = (lane == 46) ? 0.0f : NEGV;
  __builtin_amdgcn_wave_barrier();

  const float* fp = feats + (size_t)b * TT * KK + rl;
  unsigned char* bp = bptr + (size_t)b * TT * KK + lane;

  float fbuf[4];
#pragma unroll
  for (int k = 0; k < 4; ++k) fbuf[k] = fp[(size_t)k * KK];

  float fv = NEGV;
  for (int t0 = 0; t0 < TT; t0 += 4) {
#pragma unroll
    for (int u = 0; u < 4; ++u) {
      const int t = t0 + u;
      float fvr[KK];
#pragma unroll
      for (int j = 0; j < 12; ++j) {
        float4 v4 = *(const float4*)(&fvbuf[4 * j]);
        fvr[4 * j + 0] = v4.x; fvr[4 * j + 1] = v4.y;
        fvr[4 * j + 2] = v4.z; fvr[4 * j + 3] = v4.w;
      }
      __builtin_amdgcn_wave_barrier();

      float bs0 = fvr[0] + tr[0], bs1 = fvr[12] + tr[12];
      float bs2 = fvr[24] + tr[24], bs3 = fvr[36] + tr[36];
      int bi0 = 0, bi1 = 12, bi2 = 24, bi3 = 36;
#pragma unroll
      for (int p = 1; p < 12; ++p) {
        float s0 = fvr[p] + tr[p];
        float s1 = fvr[12 + p] + tr[12 + p];
        float s2 = fvr[24 + p] + tr[24 + p];
        float s3 = fvr[36 + p] + tr[36 + p];
        if (s0 > bs0) { bs0 = s0; bi0 = p; }
        if (s1 > bs1) { bs1 = s1; bi1 = 12 + p; }
        if (s2 > bs2) { bs2 = s2; bi2 = 24 + p; }
        if (s3 > bs3) { bs3 = s3; bi3 = 36 + p; }
      }
      bool c1 = bs1 > bs0;
      float m01 = c1 ? bs1 : bs0; int i01 = c1 ? bi1 : bi0;
      bool c3 = bs3 > bs2;
      float m23 = c3 ? bs3 : bs2; int i23 = c3 ? bi3 : bi2;
      bool cf = m23 > m01;
      float m = cf ? m23 : m01; int bpi = cf ? i23 : i01;

      float nfv = m + fbuf[u];
      int tpre = t + 4; if (tpre >= TT) tpre = 0;
      fbuf[u] = fp[(size_t)tpre * KK];

      if (lane < KK) {
        bp[(size_t)t * KK] = (unsigned char)bpi;
        fvbuf[lane] = nfv;
        fv = nfv;
      }
      __builtin_amdgcn_wave_barrier();
    }
  }

  float v = (lane < KK) ? (fv + tstop) : -FLT_MAX;
  int idx = lane;
#pragma unroll
  for (int off = 32; off >= 1; off >>= 1) {
    float ov = __shfl_xor(v, off);
    int oi = __shfl_xor(idx, off);
    bool take = (ov > v) || (ov == v && oi < idx);
    v = take ? ov : v;
    idx = take ? oi : idx;
  }
  if (lane == 0) { scores[b] = v; bestArr[b] = idx; }
}

__global__ __launch_bounds__(256) void bwd_map(
    const unsigned char* __restrict__ bptr, unsigned char* __restrict__ cmap) {
  const int lane = threadIdx.x & 63;
  const int wg = blockIdx.x * 4 + (threadIdx.x >> 6);
  const int b = wg >> 4;
  const int c = wg & (CC - 1);
  const int rl = (lane < KK) ? lane : (KK - 1);
  const unsigned char* bp = bptr + ((size_t)b * TT + (size_t)c * LL) * KK + rl;

  int x = rl;
  const int CH = 16;
  int cur[CH], nxt[CH];
#pragma unroll
  for (int j = 0; j < CH; ++j) cur[j] = bp[(size_t)(LL - CH + j) * KK];
  for (int tb = LL - CH; tb >= 0; tb -= CH) {
    if (tb >= CH) {
#pragma unroll
      for (int j = 0; j < CH; ++j) nxt[j] = bp[(size_t)(tb - CH + j) * KK];
    }
#pragma unroll
    for (int j = CH - 1; j >= 0; --j) x = __shfl(cur[j], x);
    if (tb >= CH) {
#pragma unroll
      for (int j = 0; j < CH; ++j) cur[j] = nxt[j];
    }
  }
  if (lane < KK) cmap[(size_t)wg * KK + lane] = (unsigned char)x;
}

__global__ __launch_bounds__(256) void bwd_entry(
    const unsigned char* __restrict__ cmap, const int* __restrict__ bestArr,
    int* __restrict__ entry) {
  const int lane = threadIdx.x & 63;
  const int b = blockIdx.x * 4 + (threadIdx.x >> 6);
  const int rl = (lane < KK) ? lane : (KK - 1);

  int rows[CC];
#pragma unroll
  for (int c = 0; c < CC; ++c) rows[c] = cmap[((size_t)b * CC + c) * KK + rl];

  int tag = bestArr[b];
  int ev = 0;
#pragma unroll
  for (int c = CC - 1; c >= 0; --c) {
    if (lane == c) ev = tag;
    tag = __shfl(rows[c], tag);
  }
  if (lane < CC) entry[b * CC + lane] = ev;
}

__global__ __launch_bounds__(256) void bwd_emit(
    const unsigned char* __restrict__ bptr, const int* __restrict__ entry,
    float* __restrict__ path) {
  const int lane = threadIdx.x & 63;
  const int wg = blockIdx.x * 4 + (threadIdx.x >> 6);
  const int b = wg >> 4;
  const int c = wg & (CC - 1);
  const int rl = (lane < KK) ? lane : (KK - 1);
  const unsigned char* bp = bptr + ((size_t)b * TT + (size_t)c * LL) * KK + rl;

  int x = entry[b * CC + c];
  int myv = 0;
  const int CH = 16;
  int cur[CH], nxt[CH];
#pragma unroll
  for (int j = 0; j < CH; ++j) cur[j] = bp[(size_t)(LL - CH + j) * KK];
  for (int tb = LL - CH; tb >= 0; tb -= CH) {
    if (tb >= CH) {
#pragma unroll
      for (int j = 0; j < CH; ++j) nxt[j] = bp[(size_t)(tb - CH + j) * KK];
    }
#pragma unroll
    for (int j = CH - 1; j >= 0; --j) {
      if (lane == tb + j) myv = x;
      x = __shfl(cur[j], x);
    }
    if (tb >= CH) {
#pragma unroll
      for (int j = 0; j < CH; ++j) cur[j] = nxt[j];
    }
  }
  path[(size_t)b * TT + (size_t)c * LL + lane] = (float)myv;
}

extern "C" void kernel_launch(void* const* d_in, const int* in_sizes, int n_in,
                              void* d_out, int out_size, void* d_ws,
                              size_t ws_size, hipStream_t stream) {
  const float* feats = (const float*)d_in[0];
  const float* trans = (const float*)d_in[1];
  float* out = (float*)d_out;  // [0,1024): scores; then paths [B*T]

  const size_t MX_BYTES = (size_t)BB * TT * KK * sizeof(float);  // 201.3 MB
  if (ws_size >= MX_BYTES) {
    float* mx = (float*)d_ws;
    viterbi_fused<<<dim3(BB), dim3(64), 0, stream>>>(feats, trans, out, mx,
                                                     out + BB);
  } else {
    unsigned char* bptr = (unsigned char*)d_ws;
    char* p = (char*)d_ws + (size_t)BB * TT * KK;
    int* bestArr = (int*)p;
    p += BB * sizeof(int);
    unsigned char* cmap = (unsigned char*)p;
    p += (size_t)BB * CC * KK;
    int* entry = (int*)p;

    viterbi_fwd_f<<<dim3(BB), dim3(64), 0, stream>>>(feats, trans, out, bptr,
                                                     bestArr);
    bwd_map<<<dim3(BB * CC / 4), dim3(256), 0, stream>>>(bptr, cmap);
    bwd_entry<<<dim3(BB / 4), dim3(256), 0, stream>>>(cmap, bestArr, entry);
    bwd_emit<<<dim3(BB * CC / 4), dim3(256), 0, stream>>>(bptr, entry,
                                                          out + BB);
  }
}